// Round 10
// baseline (82.342 us; speedup 1.0000x reference)
//
#include <hip/hip_runtime.h>
#include <hip/hip_fp16.h>
#include <stdint.h>

#define N_NODES   4096
#define N_EDGES   128
#define D_X       128
#define PE_DIM    64
#define NUM_WALKS 10
#define WALK_LEN  5
#define N_WALKS_TOT (N_NODES * NUM_WALKS)   /* 40960 */
#define OUT_COLS  (D_X + PE_DIM)            /* 192 */
#define ROW_CAP   512u                      /* adjacency row stride (u16) */
#define VCAP      512u                      /* visitor list cap (max expected ~180) */

/* workspace layout (bytes) — ~13.2 MiB */
#define OFF_MASKS   0u                                    /* 64 KiB */
#define OFF_DEG     (OFF_MASKS + N_NODES * 16u)           /* 16 KiB */
#define OFF_ADJ     (OFF_DEG + N_NODES * 4u)              /* 4 MiB */
#define OFF_WM      (OFF_ADJ + N_NODES * ROW_CAP * 2u)    /* 5 MiB */
#define OFF_VCNT    (OFF_WM + N_WALKS_TOT * PE_DIM * 2u)  /* 16 KiB */
#define OFF_VLIST   (OFF_VCNT + N_NODES * 4u)             /* 4 MiB */

/* ---- threefry2x32 (20 rounds) — cheap high-quality PRF ---- */
__device__ __forceinline__ void tf2x32(uint32_t kk0, uint32_t kk1,
                                       uint32_t x0, uint32_t x1,
                                       uint32_t& o0, uint32_t& o1) {
  const uint32_t kk2 = kk0 ^ kk1 ^ 0x1BD11BDAu;
  x0 += kk0; x1 += kk1;
  auto rnd = [&](int r) {
    x0 += x1;
    x1 = (x1 << r) | (x1 >> (32 - r));
    x1 ^= x0;
  };
  rnd(13); rnd(15); rnd(26); rnd(6);   x0 += kk1; x1 += kk2 + 1u;
  rnd(17); rnd(29); rnd(16); rnd(24);  x0 += kk2; x1 += kk0 + 2u;
  rnd(13); rnd(15); rnd(26); rnd(6);   x0 += kk0; x1 += kk1 + 3u;
  rnd(17); rnd(29); rnd(16); rnd(24);  x0 += kk1; x1 += kk2 + 4u;
  rnd(13); rnd(15); rnd(26); rnd(6);   x0 += kk2; x1 += kk0 + 5u;
  o0 = x0; o1 = x1;
}

/* ---- K1: 128-bit incidence masks (one wave per node) + vcnt zeroing ---- */
__global__ void k_masks(const float* __restrict__ inc,
                        ulonglong2* __restrict__ masks,
                        unsigned int* __restrict__ vcnt) {
  const int wid = threadIdx.x >> 6, lane = threadIdx.x & 63;
  const int i = blockIdx.x * 4 + wid;
  const float a = inc[i * N_EDGES + lane];
  const float b = inc[i * N_EDGES + 64 + lane];
  const unsigned long long m0 = __ballot(a != 0.f);
  const unsigned long long m1 = __ballot(b != 0.f);
  if (lane == 0) {
    masks[i] = make_ulonglong2(m0, m1);
    vcnt[i] = 0u;
  }
}

/* ---- K2: adjacency rows (fixed stride) + degree, masks staged in LDS ---- */
__global__ void __launch_bounds__(512)
k_adj(const ulonglong2* __restrict__ masks,
      unsigned short* __restrict__ adj, unsigned int* __restrict__ deg) {
  __shared__ ulonglong2 sm[N_NODES];
  for (int k = threadIdx.x; k < N_NODES; k += 512) sm[k] = masks[k];
  __syncthreads();
  const int wid = threadIdx.x >> 6, lane = threadIdx.x & 63;
  const int i = blockIdx.x * 8 + wid;
  const ulonglong2 mi = sm[i];
  unsigned short* row = adj + (unsigned int)i * ROW_CAP;
  unsigned int base = 0;
  for (int g = 0; g < N_NODES / 64; ++g) {
    const int j = g * 64 + lane;
    const ulonglong2 mj = sm[j];
    const bool pred = (((mi.x & mj.x) | (mi.y & mj.y)) != 0ull) && (j != i);
    const unsigned long long bal = __ballot(pred);
    if (pred) {
      const unsigned int off =
          (unsigned int)__popcll(bal & ((1ull << lane) - 1ull));
      const unsigned int pos = base + off;
      if (pos < ROW_CAP) row[pos] = (unsigned short)j;
    }
    base += (unsigned int)__popcll(bal);
  }
  if (lane == 0) deg[i] = (base < ROW_CAP) ? base : ROW_CAP;
}

/* ---- K3: per-thread walks (concurrent dependent-load chains) + per-wave
   means via LDS handoff (lane == dim). One dispatch, two phases. ---- */
__global__ void __launch_bounds__(256)
k_walkmean(const unsigned int* __restrict__ deg,
           const unsigned short* __restrict__ adj,
           const float* __restrict__ embed,
           __half* __restrict__ wm,
           unsigned int* __restrict__ vcnt, unsigned short* __restrict__ vlist) {
  __shared__ uint4 srec[256];
  const int tid = threadIdx.x, wid = tid >> 6, lane = tid & 63;
  const uint32_t w = blockIdx.x * 256u + (uint32_t)tid;

  /* phase 1: walk (one per thread) */
  uint32_t r0, r1, r2, r3;
  tf2x32(0u, 42u, w, 0u, r0, r1);
  tf2x32(0u, 42u, w, 1u, r2, r3);
  const uint32_t n0 = w / NUM_WALKS;
  uint32_t n1, n2, n3, n4, nv;
  const unsigned int d0 = deg[n0];
  if (d0 == 0) {
    n1 = n2 = n3 = n4 = n0;
    nv = 1u;
  } else {
    uint32_t cur = n0;
    unsigned int d;
    cur = adj[(cur << 9) + (uint32_t)(((uint64_t)r0 * d0) >> 32)]; n1 = cur;
    d = deg[cur];
    cur = adj[(cur << 9) + (uint32_t)(((uint64_t)r1 * d) >> 32)]; n2 = cur;
    d = deg[cur];
    cur = adj[(cur << 9) + (uint32_t)(((uint64_t)r2 * d) >> 32)]; n3 = cur;
    d = deg[cur];
    cur = adj[(cur << 9) + (uint32_t)(((uint64_t)r3 * d) >> 32)]; n4 = cur;
    nv = 5u;
  }
  uint4 rec;
  rec.x = n0 | (n1 << 16);
  rec.y = n2 | (n3 << 16);
  rec.z = n4 | (nv << 16);
  rec.w = 0u;
  srec[tid] = rec;

  /* visit records */
  unsigned int s0 = atomicAdd(&vcnt[n0], 1u);
  if (s0 < VCAP) vlist[n0 * VCAP + s0] = (unsigned short)w;
  if (nv == 5u) {
    unsigned int s1 = atomicAdd(&vcnt[n1], 1u);
    if (s1 < VCAP) vlist[n1 * VCAP + s1] = (unsigned short)w;
    unsigned int s2 = atomicAdd(&vcnt[n2], 1u);
    if (s2 < VCAP) vlist[n2 * VCAP + s2] = (unsigned short)w;
    unsigned int s3 = atomicAdd(&vcnt[n3], 1u);
    if (s3 < VCAP) vlist[n3 * VCAP + s3] = (unsigned short)w;
    unsigned int s4 = atomicAdd(&vcnt[n4], 1u);
    if (s4 < VCAP) vlist[n4 * VCAP + s4] = (unsigned short)w;
  }
  __syncthreads();

  /* phase 2: means — wave wid handles the block's walks [wid*64, wid*64+64) */
  const uint32_t wbase = blockIdx.x * 256u;
#pragma unroll 4
  for (int k = 0; k < 64; ++k) {
    const int widx = wid * 64 + k;
    const uint4 rc = srec[widx];               /* LDS broadcast */
    const uint32_t a0 = rc.x & 0xFFFFu, a1 = rc.x >> 16;
    const uint32_t a2 = rc.y & 0xFFFFu, a3 = rc.y >> 16;
    const uint32_t a4 = rc.z & 0xFFFFu, anv = rc.z >> 16;
    float s = embed[a0 * PE_DIM + lane];
    if (anv == 5u) {                           /* wave-uniform branch */
      s += embed[a1 * PE_DIM + lane];
      s += embed[a2 * PE_DIM + lane];
      s += embed[a3 * PE_DIM + lane];
      s += embed[a4 * PE_DIM + lane];
    }
    wm[(size_t)(wbase + widx) * PE_DIM + lane] = __float2half(s / (float)anv);
  }
}

/* ---- K4: block per node; 4 waves x 8-deep ILP gather of visitor means ---- */
__global__ void __launch_bounds__(256)
k_gather(const __half* __restrict__ walk_m,
         const unsigned int* __restrict__ vcnt,
         const unsigned short* __restrict__ vlist,
         const float* __restrict__ x,
         float* __restrict__ out) {
  __shared__ float red[4][PE_DIM];
  const int wid = threadIdx.x >> 6, lane = threadIdx.x & 63;
  const int v = blockIdx.x;

  /* x passthrough by wave 3 (independent of the reduction) */
  if (wid == 3) {
    const float2 xv = ((const float2*)(x + (size_t)v * D_X))[lane];
    ((float2*)(out + (size_t)v * OUT_COLS))[lane] = xv;
  }

  unsigned int c = vcnt[v];
  if (c > VCAP) c = VCAP;
  const unsigned short* vl = vlist + (unsigned int)v * VCAP;

  float s = 0.f;
  for (unsigned int base = (unsigned int)wid * 8u; base < c; base += 32u) {
#pragma unroll
    for (int q = 0; q < 8; ++q) {
      const unsigned int idx = base + (unsigned int)q;
      const bool ok = idx < c;
      const unsigned int ww = ok ? (unsigned int)vl[idx] : (unsigned int)vl[0];
      const float val = __half2float(walk_m[(size_t)ww * PE_DIM + lane]);
      s += ok ? val : 0.f;
    }
  }
  red[wid][lane] = s;
  __syncthreads();
  if (wid == 0) {
    const float t = red[0][lane] + red[1][lane] + red[2][lane] + red[3][lane];
    out[(size_t)v * OUT_COLS + D_X + lane] = c ? t / (float)c : 0.f;
  }
}

extern "C" void kernel_launch(void* const* d_in, const int* in_sizes, int n_in,
                              void* d_out, int out_size, void* d_ws, size_t ws_size,
                              hipStream_t stream) {
  const float* x   = (const float*)d_in[0];
  const float* inc = (const float*)d_in[1];
  const float* emb = (const float*)d_in[2];
  float* out = (float*)d_out;

  char* ws = (char*)d_ws;
  ulonglong2*     masks = (ulonglong2*)(ws + OFF_MASKS);
  unsigned int*   deg   = (unsigned int*)(ws + OFF_DEG);
  unsigned short* adj   = (unsigned short*)(ws + OFF_ADJ);
  __half*         wm    = (__half*)(ws + OFF_WM);
  unsigned int*   vcnt  = (unsigned int*)(ws + OFF_VCNT);
  unsigned short* vlist = (unsigned short*)(ws + OFF_VLIST);

  k_masks   <<<N_NODES / 4, 256, 0, stream>>>(inc, masks, vcnt);
  k_adj     <<<N_NODES / 8, 512, 0, stream>>>(masks, adj, deg);
  k_walkmean<<<N_WALKS_TOT / 256, 256, 0, stream>>>(deg, adj, emb, wm, vcnt,
                                                    vlist);
  k_gather  <<<N_NODES, 256, 0, stream>>>(wm, vcnt, vlist, x, out);
}

// Round 11
// 66.868 us; speedup vs baseline: 1.2314x; 1.2314x over previous
//
#include <hip/hip_runtime.h>
#include <hip/hip_fp16.h>
#include <stdint.h>

#define N_NODES   4096
#define N_EDGES   128
#define D_X       128
#define PE_DIM    64
#define NUM_WALKS 10
#define WALK_LEN  5
#define N_WALKS_TOT (N_NODES * NUM_WALKS)   /* 40960 */
#define OUT_COLS  (D_X + PE_DIM)            /* 192 */
#define ROW_CAP   512u                      /* adjacency row stride (u16) */
#define VCAP      512u                      /* visitor list cap (max expected ~180) */

/* workspace layout (bytes) — ~13.2 MiB */
#define OFF_MASKS   0u                                    /* 64 KiB */
#define OFF_DEG     (OFF_MASKS + N_NODES * 16u)           /* 16 KiB */
#define OFF_ADJ     (OFF_DEG + N_NODES * 4u)              /* 4 MiB */
#define OFF_WM      (OFF_ADJ + N_NODES * ROW_CAP * 2u)    /* 5 MiB */
#define OFF_VCNT    (OFF_WM + N_WALKS_TOT * PE_DIM * 2u)  /* 16 KiB */
#define OFF_VLIST   (OFF_VCNT + N_NODES * 4u)             /* 4 MiB */

/* ---- threefry2x32 (20 rounds) — cheap high-quality PRF ---- */
__device__ __forceinline__ void tf2x32(uint32_t kk0, uint32_t kk1,
                                       uint32_t x0, uint32_t x1,
                                       uint32_t& o0, uint32_t& o1) {
  const uint32_t kk2 = kk0 ^ kk1 ^ 0x1BD11BDAu;
  x0 += kk0; x1 += kk1;
  auto rnd = [&](int r) {
    x0 += x1;
    x1 = (x1 << r) | (x1 >> (32 - r));
    x1 ^= x0;
  };
  rnd(13); rnd(15); rnd(26); rnd(6);   x0 += kk1; x1 += kk2 + 1u;
  rnd(17); rnd(29); rnd(16); rnd(24);  x0 += kk2; x1 += kk0 + 2u;
  rnd(13); rnd(15); rnd(26); rnd(6);   x0 += kk0; x1 += kk1 + 3u;
  rnd(17); rnd(29); rnd(16); rnd(24);  x0 += kk1; x1 += kk2 + 4u;
  rnd(13); rnd(15); rnd(26); rnd(6);   x0 += kk2; x1 += kk0 + 5u;
  o0 = x0; o1 = x1;
}

/* ---- K1: 128-bit incidence masks (one wave per node) + vcnt zeroing ---- */
__global__ void k_masks(const float* __restrict__ inc,
                        ulonglong2* __restrict__ masks,
                        unsigned int* __restrict__ vcnt) {
  const int wid = threadIdx.x >> 6, lane = threadIdx.x & 63;
  const int i = blockIdx.x * 4 + wid;
  const float a = inc[i * N_EDGES + lane];
  const float b = inc[i * N_EDGES + 64 + lane];
  const unsigned long long m0 = __ballot(a != 0.f);
  const unsigned long long m1 = __ballot(b != 0.f);
  if (lane == 0) {
    masks[i] = make_ulonglong2(m0, m1);
    vcnt[i] = 0u;
  }
}

/* ---- K2: adjacency rows (fixed stride) + degree, masks staged in LDS ---- */
__global__ void __launch_bounds__(512)
k_adj(const ulonglong2* __restrict__ masks,
      unsigned short* __restrict__ adj, unsigned int* __restrict__ deg) {
  __shared__ ulonglong2 sm[N_NODES];
  for (int k = threadIdx.x; k < N_NODES; k += 512) sm[k] = masks[k];
  __syncthreads();
  const int wid = threadIdx.x >> 6, lane = threadIdx.x & 63;
  const int i = blockIdx.x * 8 + wid;
  const ulonglong2 mi = sm[i];
  unsigned short* row = adj + (unsigned int)i * ROW_CAP;
  unsigned int base = 0;
  for (int g = 0; g < N_NODES / 64; ++g) {
    const int j = g * 64 + lane;
    const ulonglong2 mj = sm[j];
    const bool pred = (((mi.x & mj.x) | (mi.y & mj.y)) != 0ull) && (j != i);
    const unsigned long long bal = __ballot(pred);
    if (pred) {
      const unsigned int off =
          (unsigned int)__popcll(bal & ((1ull << lane) - 1ull));
      const unsigned int pos = base + off;
      if (pos < ROW_CAP) row[pos] = (unsigned short)j;
    }
    base += (unsigned int)__popcll(bal);
  }
  if (lane == 0) deg[i] = (base < ROW_CAP) ? base : ROW_CAP;
}

/* ---- K3: 64 walks per block (wave 0, per-thread chains) + means by all
   4 waves (16 walks each, lane == dim). 640 blocks -> real occupancy. ---- */
__global__ void __launch_bounds__(256)
k_walkmean(const unsigned int* __restrict__ deg,
           const unsigned short* __restrict__ adj,
           const float* __restrict__ embed,
           __half* __restrict__ wm,
           unsigned int* __restrict__ vcnt, unsigned short* __restrict__ vlist) {
  __shared__ uint4 srec[64];
  const int tid = threadIdx.x, wid = tid >> 6, lane = tid & 63;
  const uint32_t wbase = blockIdx.x * 64u;

  /* phase 1: walks, one per thread of wave 0 */
  if (tid < 64) {
    const uint32_t w = wbase + (uint32_t)tid;
    uint32_t r0, r1, r2, r3;
    tf2x32(0u, 42u, w, 0u, r0, r1);
    tf2x32(0u, 42u, w, 1u, r2, r3);
    const uint32_t n0 = w / NUM_WALKS;
    uint32_t n1, n2, n3, n4, nv;
    const unsigned int d0 = deg[n0];
    if (d0 == 0) {
      n1 = n2 = n3 = n4 = n0;
      nv = 1u;
    } else {
      uint32_t cur = n0;
      unsigned int d;
      cur = adj[(cur << 9) + (uint32_t)(((uint64_t)r0 * d0) >> 32)]; n1 = cur;
      d = deg[cur];
      cur = adj[(cur << 9) + (uint32_t)(((uint64_t)r1 * d) >> 32)]; n2 = cur;
      d = deg[cur];
      cur = adj[(cur << 9) + (uint32_t)(((uint64_t)r2 * d) >> 32)]; n3 = cur;
      d = deg[cur];
      cur = adj[(cur << 9) + (uint32_t)(((uint64_t)r3 * d) >> 32)]; n4 = cur;
      nv = 5u;
    }
    uint4 rec;
    rec.x = n0 | (n1 << 16);
    rec.y = n2 | (n3 << 16);
    rec.z = n4 | (nv << 16);
    rec.w = 0u;
    srec[tid] = rec;

    /* visit records */
    unsigned int s0 = atomicAdd(&vcnt[n0], 1u);
    if (s0 < VCAP) vlist[n0 * VCAP + s0] = (unsigned short)w;
    if (nv == 5u) {
      unsigned int s1 = atomicAdd(&vcnt[n1], 1u);
      if (s1 < VCAP) vlist[n1 * VCAP + s1] = (unsigned short)w;
      unsigned int s2 = atomicAdd(&vcnt[n2], 1u);
      if (s2 < VCAP) vlist[n2 * VCAP + s2] = (unsigned short)w;
      unsigned int s3 = atomicAdd(&vcnt[n3], 1u);
      if (s3 < VCAP) vlist[n3 * VCAP + s3] = (unsigned short)w;
      unsigned int s4 = atomicAdd(&vcnt[n4], 1u);
      if (s4 < VCAP) vlist[n4 * VCAP + s4] = (unsigned short)w;
    }
  }
  __syncthreads();

  /* phase 2: means — wave wid handles walks [wid*16, wid*16+16) */
#pragma unroll 4
  for (int k = 0; k < 16; ++k) {
    const int widx = wid * 16 + k;
    const uint4 rc = srec[widx];               /* LDS broadcast */
    const uint32_t a0 = rc.x & 0xFFFFu, a1 = rc.x >> 16;
    const uint32_t a2 = rc.y & 0xFFFFu, a3 = rc.y >> 16;
    const uint32_t a4 = rc.z & 0xFFFFu, anv = rc.z >> 16;
    float s = embed[a0 * PE_DIM + lane];
    if (anv == 5u) {                           /* wave-uniform branch */
      s += embed[a1 * PE_DIM + lane];
      s += embed[a2 * PE_DIM + lane];
      s += embed[a3 * PE_DIM + lane];
      s += embed[a4 * PE_DIM + lane];
    }
    wm[(size_t)(wbase + widx) * PE_DIM + lane] = __float2half(s / (float)anv);
  }
}

/* ---- K4: block per node; 4 waves x 8-deep ILP gather of visitor means ---- */
__global__ void __launch_bounds__(256)
k_gather(const __half* __restrict__ walk_m,
         const unsigned int* __restrict__ vcnt,
         const unsigned short* __restrict__ vlist,
         const float* __restrict__ x,
         float* __restrict__ out) {
  __shared__ float red[4][PE_DIM];
  const int wid = threadIdx.x >> 6, lane = threadIdx.x & 63;
  const int v = blockIdx.x;

  /* x passthrough by wave 3 (independent of the reduction) */
  if (wid == 3) {
    const float2 xv = ((const float2*)(x + (size_t)v * D_X))[lane];
    ((float2*)(out + (size_t)v * OUT_COLS))[lane] = xv;
  }

  unsigned int c = vcnt[v];
  if (c > VCAP) c = VCAP;
  const unsigned short* vl = vlist + (unsigned int)v * VCAP;

  float s = 0.f;
  for (unsigned int base = (unsigned int)wid * 8u; base < c; base += 32u) {
#pragma unroll
    for (int q = 0; q < 8; ++q) {
      const unsigned int idx = base + (unsigned int)q;
      const bool ok = idx < c;
      const unsigned int ww = ok ? (unsigned int)vl[idx] : (unsigned int)vl[0];
      const float val = __half2float(walk_m[(size_t)ww * PE_DIM + lane]);
      s += ok ? val : 0.f;
    }
  }
  red[wid][lane] = s;
  __syncthreads();
  if (wid == 0) {
    const float t = red[0][lane] + red[1][lane] + red[2][lane] + red[3][lane];
    out[(size_t)v * OUT_COLS + D_X + lane] = c ? t / (float)c : 0.f;
  }
}

extern "C" void kernel_launch(void* const* d_in, const int* in_sizes, int n_in,
                              void* d_out, int out_size, void* d_ws, size_t ws_size,
                              hipStream_t stream) {
  const float* x   = (const float*)d_in[0];
  const float* inc = (const float*)d_in[1];
  const float* emb = (const float*)d_in[2];
  float* out = (float*)d_out;

  char* ws = (char*)d_ws;
  ulonglong2*     masks = (ulonglong2*)(ws + OFF_MASKS);
  unsigned int*   deg   = (unsigned int*)(ws + OFF_DEG);
  unsigned short* adj   = (unsigned short*)(ws + OFF_ADJ);
  __half*         wm    = (__half*)(ws + OFF_WM);
  unsigned int*   vcnt  = (unsigned int*)(ws + OFF_VCNT);
  unsigned short* vlist = (unsigned short*)(ws + OFF_VLIST);

  k_masks   <<<N_NODES / 4, 256, 0, stream>>>(inc, masks, vcnt);
  k_adj     <<<N_NODES / 8, 512, 0, stream>>>(masks, adj, deg);
  k_walkmean<<<N_WALKS_TOT / 64, 256, 0, stream>>>(deg, adj, emb, wm, vcnt,
                                                   vlist);
  k_gather  <<<N_NODES, 256, 0, stream>>>(wm, vcnt, vlist, x, out);
}